// Round 12
// baseline (279.203 us; speedup 1.0000x reference)
//
#include <hip/hip_runtime.h>
#include <math.h>

#define EPSF   1e-15f
#define CLIP1  0.99999988f   /* fp32(1 - 1e-7) */
#define MAXNRM 0.99999f      /* (1 - 1e-5)/sqrt(c), c = 1 */
#define LOG2E  1.44269504088896f
#define LN2    0.69314718055994f

typedef __bf16 bf16x8 __attribute__((ext_vector_type(8)));
typedef float floatx4 __attribute__((ext_vector_type(4)));
typedef _Float16 half4 __attribute__((ext_vector_type(4)));

// Vp2 element index: [b][h:34][cb:32][w:34][8]  (ushort elements)
// addr = (((b*34 + h)*32 + cb)*34 + w)*8 + e ; cb-stride = 272, h-stride = 8704

// ---------------------------------------------------------------- utilities
__device__ __forceinline__ float wred(float x) {
#pragma unroll
  for (int o = 32; o; o >>= 1) x += __shfl_xor(x, o);
  return x;
}

__device__ __forceinline__ float frcp(float x) { return __builtin_amdgcn_rcpf(x); }
__device__ __forceinline__ float flog2(float x) { return __builtin_amdgcn_logf(x); }
__device__ __forceinline__ float fexp2(float x) { return __builtin_amdgcn_exp2f(x); }

__device__ __forceinline__ float atanh_fast(float x) {   // x in [0, CLIP1]
  return 0.5f * LN2 * flog2((1.f + x) * frcp(1.f - x));
}
__device__ __forceinline__ float tanh_fast(float x) {    // x >= 0
  float q = fexp2(fminf(2.f * LOG2E * x, 126.f));
  return (q - 1.f) * frcp(q + 1.f);
}
// sinh(2*z*asinh(w)), z > 0
__device__ __forceinline__ float sinh2zasinh(float z, float w) {
  float aw = fabsf(w);
  float tt = aw + sqrtf(fmaf(aw, aw, 1.f));
  float k2 = fminf(2.f * z * flog2(tt), 126.f);
  float q = fexp2(k2);
  return copysignf(0.5f * (q - frcp(q)), w);
}

__device__ __forceinline__ unsigned short f2bf(float f) {
  unsigned int u = __float_as_uint(f);
  u += 0x7fffu + ((u >> 16) & 1u);   // RNE
  return (unsigned short)(u >> 16);
}

__device__ __forceinline__ void gl_lds16(const ushort* g, ushort* l) {
  __builtin_amdgcn_global_load_lds(
      (const __attribute__((address_space(1))) void*)g,
      (__attribute__((address_space(3))) void*)l, 16, 0, 0);
}

// ---------------------------------------------------------------- Z -> fragment-ordered bf16 (+ column norms^2)
__global__ __launch_bounds__(256) void k_zpack(const float* __restrict__ Z1,
                                               const float* __restrict__ Z2,
                                               ushort* __restrict__ ZF,
                                               float* __restrict__ ZN2) {
  __shared__ float zs[32 * 256];
  int kt = blockIdx.x, mat = blockIdx.y;
  const float* Z = mat ? Z2 : Z1;
  ushort* out = ZF + (size_t)mat * 589824;
  int t = threadIdx.x;
  const float4* src = (const float4*)(Z + kt * 32 * 256);
  float4* dst4 = (float4*)zs;
#pragma unroll
  for (int i = 0; i < 8; ++i) dst4[t + i * 256] = src[t + i * 256];
  __syncthreads();
  {
    float acc = 0.f;
#pragma unroll 8
    for (int k = 0; k < 32; ++k) {
      float z = zs[k * 256 + t];
      acc = fmaf(z, z, acc);
    }
    atomicAdd(&ZN2[mat * 256 + t], acc);
  }
  int l = t & 63, sub = t >> 6;
  for (int i = 0; i < 4; ++i) {
    int combo = sub * 4 + i;                 // ctg 0..15
    int col = combo * 16 + (l & 15);
    int krow = (l >> 4) * 8;
    unsigned int pk[4];
#pragma unroll
    for (int j = 0; j < 4; ++j) {
      unsigned int lo = f2bf(zs[(krow + 2 * j) * 256 + col]);
      unsigned int hi = f2bf(zs[(krow + 2 * j + 1) * 256 + col]);
      pk[j] = lo | (hi << 16);
    }
    uint4* o = (uint4*)(out + ((size_t)(kt * 16 + combo)) * 512 + l * 8);
    *o = make_uint4(pk[0], pk[1], pk[2], pk[3]);
  }
}

// ---------------------------------------------------------------- x[B,C,H,W] -> Vp2 bf16 (channel-blocked) + border zero, nv2
__global__ __launch_bounds__(256) void k_pre1(const float* __restrict__ X,
                                              ushort* __restrict__ Vp,
                                              float* __restrict__ NV2,
                                              float scale) {
  __shared__ float tile[256 * 33];
  __shared__ float facs[32];
  const int b = blockIdx.x >> 5, h = blockIdx.x & 31;
  const int t = threadIdx.x;
  for (int c0 = 0; c0 < 256; c0 += 8) {
    int c = c0 + (t >> 5), w = t & 31;
    tile[c * 33 + w] = X[((b * 256 + c) * 32 + h) * 32 + w];
  }
  // border zeroing (replaces Vp memset): w=0/33 of this row; h=0/33 planes by edge blocks
  {
    ushort4 z4 = {0, 0, 0, 0};
    if (t < 128) {
      int wb = (t >> 6) ? 33 : 0;          // w border
      int cb = (t & 63) >> 1, e = (t & 1) * 4;
      *(ushort4*)(Vp + ((size_t)((b * 34 + h + 1) * 32 + cb) * 34 + wb) * 8 + e) = z4;
    }
    if (h == 0) {
      size_t base = (size_t)(b * 34) * 8704;
      for (int i = t; i < 2176; i += 256) *(ushort4*)(Vp + base + i * 4) = z4;
    }
    if (h == 31) {
      size_t base = (size_t)(b * 34 + 33) * 8704;
      for (int i = t; i < 2176; i += 256) *(ushort4*)(Vp + base + i * 4) = z4;
    }
  }
  __syncthreads();
  {
    int w = t >> 3, s = t & 7;
    float n2 = 0.f;
#pragma unroll 8
    for (int i = 0; i < 32; ++i) {
      float xv = tile[(s + 8 * i) * 33 + w];
      n2 = fmaf(xv, xv, n2);
    }
    n2 += __shfl_xor(n2, 1); n2 += __shfl_xor(n2, 2); n2 += __shfl_xor(n2, 4);
    float n = sqrtf(fmaxf(n2, EPSF));
    float fac = atanh_fast(fminf(n, CLIP1)) * frcp(n) * scale;
    if (s == 0) {
      facs[w] = fac;
      NV2[blockIdx.x * 32 + w] = fac * fac * n2;
    }
  }
  __syncthreads();
  const int g = t & 63;
  const int cb = g >> 1, e = (g & 1) * 4;
  const int Hrow = (b * 34 + h + 1) * 32;
#pragma unroll
  for (int it = 0; it < 8; ++it) {
    int p = (t >> 6) + it * 4;
    float f = facs[p];
    ushort4 vb;
    vb.x = f2bf(tile[(g * 4 + 0) * 33 + p] * f);
    vb.y = f2bf(tile[(g * 4 + 1) * 33 + p] * f);
    vb.z = f2bf(tile[(g * 4 + 2) * 33 + p] * f);
    vb.w = f2bf(tile[(g * 4 + 3) * 33 + p] * f);
    *(ushort4*)(Vp + ((size_t)(Hrow + cb) * 34 + (p + 1)) * 8 + e) = vb;
  }
}

// ---------------------------------------------------------------- MFMA implicit-GEMM conv + fused Poincare-FC front
// tile 128 rows x 64 cols, 4 waves x 32 rows (B-frag reuse x2), grid 512 (2 blocks/CU).
__global__ __launch_bounds__(256) void k_gemm_mfma(const ushort* __restrict__ Vp,
                                                   const ushort* __restrict__ ZF,
                                                   const float* __restrict__ ZN2,
                                                   const float* __restrict__ NV2,
                                                   _Float16* __restrict__ Y,
                                                   float* __restrict__ Y2S) {
  __shared__ ushort ldsB[8192];   // 2 bufs x 4KB
  __shared__ float lfs[128];
  const int t = threadIdx.x;
  const int wv = t >> 6, l = t & 63;
  const int l15 = l & 15, l16 = l >> 4;
  const int g = blockIdx.x;
  const int xcd = g & 7, gi = g >> 3;
  const int rowb = (gi >> 2) * 8 + xcd;       // 0..127
  const int colb = gi & 3;                    // 0..3
  const int col0 = colb * 64, row0 = rowb * 128;
  const int cb4 = colb * 4;

  if (t < 128) {
    int r = row0 + t;
    int hw = r & 1023, hh = hw >> 5, ww = hw & 31, base = r & ~1023;
    float s = 0.f;
#pragma unroll
    for (int di = -1; di <= 1; ++di)
#pragma unroll
      for (int dj = -1; dj <= 1; ++dj) {
        int sh = hh + di, sw = ww + dj;
        if ((unsigned)sh < 32u && (unsigned)sw < 32u) s += NV2[base + sh * 32 + sw];
      }
    float np = sqrtf(fmaxf(s, EPSF));
    float un = tanh_fast(np);
    float f = un * frcp(np);
    if (un > MAXNRM) f *= MAXNRM / un;
    float u2 = f * f * s;
    lfs[t] = 2.f * frcp(fmaxf(1.f - u2, EPSF)) * f;
  }

  const int rbase = row0 + wv * 32;
  const int pb = rbase >> 10, ph = (rbase >> 5) & 31;
  const int Hrow = (pb * 34 + ph + 1) * 32;
  int abase[2];
#pragma unroll
  for (int rt = 0; rt < 2; ++rt)
    abase[rt] = Hrow * 272 + (1 + rt * 16 + l15) * 8 + l16 * 272;

  floatx4 acc[2][4];
#pragma unroll
  for (int rt = 0; rt < 2; ++rt)
#pragma unroll
    for (int j = 0; j < 4; ++j) acc[rt][j] = (floatx4){0.f, 0.f, 0.f, 0.f};

  auto loadA = [&](bf16x8 (&ar)[2][2], int kt) {   // [s][rt]
    int tap = kt >> 2;
    int di = tap / 3 - 1, dj = tap % 3 - 1;
    int koff = (di * 32 + (kt & 3) * 8) * 272 + dj * 8;   // wave-uniform
#pragma unroll
    for (int s = 0; s < 2; ++s)
#pragma unroll
      for (int rt = 0; rt < 2; ++rt)
        ar[s][rt] = *(const bf16x8*)(Vp + abase[rt] + koff + s * 1088);
  };
  auto stageB = [&](int buf, int kt) {
    ushort* Bd = ldsB + buf * 4096;
#pragma unroll
    for (int ii = 0; ii < 2; ++ii) {
      int bj = wv + ii * 4;                 // 0..7 = s*4 + ct
      int s = bj >> 2, ct = bj & 3;
      gl_lds16(ZF + ((size_t)((kt * 2 + s) * 16 + cb4 + ct)) * 512 + l * 8,
               Bd + bj * 512);
    }
  };
  auto compute = [&](const bf16x8 (&ar)[2][2], const ushort* Bb) {
    bf16x8 b[2][4];
#pragma unroll
    for (int s = 0; s < 2; ++s)
#pragma unroll
      for (int j = 0; j < 4; ++j)
        b[s][j] = *(const bf16x8*)(Bb + (s * 4 + j) * 512 + l * 8);
#pragma unroll
    for (int s = 0; s < 2; ++s)
#pragma unroll
      for (int rt = 0; rt < 2; ++rt)
#pragma unroll
        for (int j = 0; j < 4; ++j)
          acc[rt][j] = __builtin_amdgcn_mfma_f32_16x16x32_bf16(ar[s][rt], b[s][j],
                                                               acc[rt][j], 0, 0, 0);
  };

  bf16x8 aA[2][2], aB[2][2];
  stageB(0, 0);
  loadA(aA, 0);
  for (int kt = 0; kt < 36; kt += 2) {
    __syncthreads();                         // B(kt) resident in buf 0
    stageB(1, kt + 1);
    loadA(aB, kt + 1);
    compute(aA, ldsB);
    __syncthreads();                         // B(kt+1) resident in buf 1
    if (kt + 2 < 36) {
      stageB(0, kt + 2);
      loadA(aA, kt + 2);
    }
    compute(aB, ldsB + 4096);
  }

  float zns[4], izns[4];
#pragma unroll
  for (int j = 0; j < 4; ++j) {
    int c = col0 + j * 16 + l15;
    float zn = sqrtf(fmaxf(ZN2[c], EPSF));
    zns[j] = zn;
    izns[j] = frcp(zn);
  }
#pragma unroll
  for (int rt = 0; rt < 2; ++rt) {
#pragma unroll
    for (int reg = 0; reg < 4; ++reg) {
      int rl = wv * 32 + rt * 16 + l16 * 4 + reg;
      int r = row0 + rl;
      float lf = lfs[rl];
      float part = 0.f;
#pragma unroll
      for (int j = 0; j < 4; ++j) {
        float yv = sinh2zasinh(zns[j], lf * acc[rt][j][reg] * izns[j]);
        Y[(size_t)r * 256 + col0 + j * 16 + l15] = (_Float16)yv;
        part = fmaf(yv, yv, part);
      }
      part += __shfl_xor(part, 1);
      part += __shfl_xor(part, 2);
      part += __shfl_xor(part, 4);
      part += __shfl_xor(part, 8);
      if (l15 == 0) Y2S[r * 4 + colb] = part;
    }
  }
}

// ---------------------------------------------------------------- recompute h from (Y, Y2 slices)
__device__ __forceinline__ void load_h(const _Float16* Y, const float* Y2S,
                                       int pix, int lane, float h[4],
                                       float& hn2, float& lam) {
  half4 y4 = ((const half4*)Y)[pix * 64 + lane];
  float4 q = ((const float4*)Y2S)[pix];
  float y2 = (q.x + q.y) + (q.z + q.w);
  float inv = frcp(1.f + sqrtf(1.f + y2));
  h[0] = (float)y4.x * inv; h[1] = (float)y4.y * inv;
  h[2] = (float)y4.z * inv; h[3] = (float)y4.w * inv;
  hn2 = y2 * inv * inv;
  lam = 2.f * frcp(fmaxf(1.f - hn2, EPSF));
}

// ---------------------------------------------------------------- BN reduction 1: 128 blocks x 128 pixels
__global__ __launch_bounds__(256) void k_bnsum(const _Float16* __restrict__ Y,
                                               const float* __restrict__ Y2S,
                                               float* __restrict__ PNUM,
                                               float* __restrict__ PDEN) {
  __shared__ float snum[256];
  __shared__ float sden;
  int t = threadIdx.x, lane = t & 63, wv = t >> 6;
  snum[t] = 0.f;
  if (t == 0) sden = 0.f;
  __syncthreads();
  float acc[4] = {0.f, 0.f, 0.f, 0.f};
  float accd = 0.f;
  for (int it = 0; it < 32; ++it) {
    int pix = blockIdx.x * 128 + it * 4 + wv;
    float h[4], hn2, lam;
    load_h(Y, Y2S, pix, lane, h, hn2, lam);
#pragma unroll
    for (int k = 0; k < 4; ++k) acc[k] = fmaf(lam, h[k], acc[k]);
    if (lane == 0) accd += lam - 1.f;
  }
  atomicAdd(&snum[lane * 4 + 0], acc[0]);
  atomicAdd(&snum[lane * 4 + 1], acc[1]);
  atomicAdd(&snum[lane * 4 + 2], acc[2]);
  atomicAdd(&snum[lane * 4 + 3], acc[3]);
  if (lane == 0) atomicAdd(&sden, accd);
  __syncthreads();
  PNUM[t * 128 + blockIdx.x] = snum[t];
  if (t == 0) PDEN[blockIdx.x] = sden;
}

// ---------------------------------------------------------------- BN midpoint + scalars (reduces 128 partials)
__global__ __launch_bounds__(256) void k_bnmid(const float* __restrict__ PNUM,
                                               const float* __restrict__ PDEN,
                                               const float* __restrict__ BIAS,
                                               float* __restrict__ MU,
                                               float* __restrict__ SCAL) {
  __shared__ float sb[4];
  int t = threadIdx.x, lane = t & 63, wv = t >> 6;
  auto bred = [&](float v) {
    v = wred(v);
    __syncthreads();
    if (lane == 0) sb[wv] = v;
    __syncthreads();
    return sb[0] + sb[1] + sb[2] + sb[3];
  };
  float num = 0.f;
  const float4* pn = (const float4*)(PNUM + t * 128);
#pragma unroll 8
  for (int i = 0; i < 32; ++i) {
    float4 v = pn[i];
    num += (v.x + v.y) + (v.z + v.w);
  }
  float den = bred(t < 128 ? PDEN[t] : 0.f);
  float m = num / fmaxf(den, EPSF);
  float n2m = bred(m * m);
  float n = sqrtf(fmaxf(n2m, EPSF));
  float midf = tanh_fast(0.5f * atanh_fast(fminf(n, CLIP1))) * frcp(n);
  float mu = m * midf;
  MU[t] = mu;
  float bv = BIAS[t];
  float bias2 = bred(bv * bv);
  float mubias = bred(bv * mu);
  if (t == 0) {
    float mu2 = midf * midf * n2m;
    SCAL[0] = mu2;
    SCAL[1] = 2.f / fmaxf(1.f - mu2, EPSF);
    SCAL[2] = bias2;
    SCAL[3] = 2.f / fmaxf(1.f - bias2, EPSF);
    SCAL[4] = mubias;
  }
}

// ---------------------------------------------------------------- BN reduction 2: 128 blocks x 128 pixels
__global__ __launch_bounds__(256) void k_bnvar(const _Float16* __restrict__ Y,
                                               const float* __restrict__ Y2S,
                                               const float* __restrict__ MU,
                                               const float* __restrict__ SCAL,
                                               float* __restrict__ PVAR) {
  __shared__ float sp[4];
  int t = threadIdx.x, lane = t & 63, wv = t >> 6;
  float4 muv = ((const float4*)MU)[lane];
  float mu2 = SCAL[0];
  float accd = 0.f;
  for (int it = 0; it < 32; ++it) {
    int pix = blockIdx.x * 128 + it * 4 + wv;
    float h[4], x2, lam;
    load_h(Y, Y2S, pix, lane, h, x2, lam);
    float xmu = wred(h[0] * muv.x + h[1] * muv.y + h[2] * muv.z + h[3] * muv.w);
    float A = 1.f - 2.f * xmu + mu2;
    float B = 1.f - x2;
    float num2 = A * A * x2 + B * B * mu2 - 2.f * A * B * xmu;
    float den = fmaxf(1.f - 2.f * xmu + x2 * mu2, EPSF);
    float nn = sqrtf(fmaxf(num2, EPSF)) * frcp(den);
    float dist = 2.f * atanh_fast(fminf(nn, CLIP1));
    accd += dist * dist;
  }
  if (lane == 0) sp[wv] = accd;
  __syncthreads();
  if (t == 0) PVAR[blockIdx.x] = sp[0] + sp[1] + sp[2] + sp[3];
}

// ---------------------------------------------------------------- BN transform core
template <bool CLIPR>
__device__ __forceinline__ void bn_core(const float x[4], const float mm[4],
                                        const float bs[4], float mu2, float lam_mu,
                                        float bias2, float lam_bias, float mubias,
                                        float rstd, float r[4], float& nr) {
  float x2 = wred(x[0] * x[0] + x[1] * x[1] + x[2] * x[2] + x[3] * x[3]);
  float xmu = wred(x[0] * mm[0] + x[1] * mm[1] + x[2] * mm[2] + x[3] * mm[3]);
  float P = 1.f - 2.f * xmu + x2, Q = 1.f - mu2;
  float den1i = frcp(fmaxf(1.f - 2.f * xmu + mu2 * x2, EPSF));
  float d[4];
#pragma unroll
  for (int k = 0; k < 4; ++k) d[k] = (Q * x[k] - P * mm[k]) * den1i;
  float nd2 = wred(d[0] * d[0] + d[1] * d[1] + d[2] * d[2] + d[3] * d[3]);
  float nd = sqrtf(fmaxf(nd2, EPSF));
  float vfac = (2.f / lam_mu) * atanh_fast(fminf(nd, CLIP1)) * frcp(nd);
  float v[4];
#pragma unroll
  for (int k = 0; k < 4; ++k) v[k] = vfac * d[k];
  float uw = wred(bs[0] * v[0] + bs[1] * v[1] + bs[2] * v[2] + bs[3] * v[3]);
  float mv = wred(mm[0] * v[0] + mm[1] * v[1] + mm[2] * v[2] + mm[3] * v[3]);
  float vw = -mv, uv = -mubias;
  float ga = -(uw * mu2) - vw + 2.f * uv * vw;
  float gb = -(vw * bias2) + uw;
  float ddi = frcp(fmaxf(1.f + 2.f * uv + bias2 * mu2, EPSF));
  float sgy = (lam_mu / lam_bias) * rstd;
  float u[4];
#pragma unroll
  for (int k = 0; k < 4; ++k)
    u[k] = (v[k] + 2.f * (ga * bs[k] - gb * mm[k]) * ddi) * sgy;
  float nu2 = wred(u[0] * u[0] + u[1] * u[1] + u[2] * u[2] + u[3] * u[3]);
  float bu = wred(bs[0] * u[0] + bs[1] * u[1] + bs[2] * u[2] + bs[3] * u[3]);
  float nu = sqrtf(fmaxf(nu2, EPSF));
  float sfac = tanh_fast(lam_bias * nu * 0.5f) * frcp(nu);
  float y2 = sfac * sfac * nu2, xy = sfac * bu;
  float P2 = 1.f + 2.f * xy + y2, Q2 = 1.f - bias2;
  float den2i = frcp(fmaxf(1.f + 2.f * xy + bias2 * y2, EPSF));
#pragma unroll
  for (int k = 0; k < 4; ++k) r[k] = (P2 * bs[k] + Q2 * sfac * u[k]) * den2i;
  float nr2 = wred(r[0] * r[0] + r[1] * r[1] + r[2] * r[2] + r[3] * r[3]);
  nr = sqrtf(fmaxf(nr2, EPSF));
  if (CLIPR && nr > MAXNRM) {
    float sc = MAXNRM / nr;
#pragma unroll
    for (int k = 0; k < 4; ++k) r[k] *= sc;
    nr = MAXNRM;
  }
}

// reduce 128 PVAR partials to var (all threads get result)
__device__ __forceinline__ float pvar_reduce(const float* PVAR, float* sbv) {
  int t = threadIdx.x, lane = t & 63, wv = t >> 6;
  float pv = wred(t < 128 ? PVAR[t] : 0.f);
  __syncthreads();
  if (lane == 0) sbv[wv] = pv;
  __syncthreads();
  return (sbv[0] + sbv[1] + sbv[2] + sbv[3]) * (1.f / 16384.f);
}

// ---------------------------------------------------------------- BN1 transform + hrelu + logmap0*scale -> Vp2,NV2
// 512 blocks x 32 pixels
__global__ __launch_bounds__(256) void k_bntrans_pre(const _Float16* __restrict__ Y,
                                                     const float* __restrict__ Y2S,
                                                     const float* __restrict__ MU,
                                                     const float* __restrict__ SCAL,
                                                     const float* __restrict__ BIAS,
                                                     const float* __restrict__ WEIGHT,
                                                     const float* __restrict__ PVAR,
                                                     ushort* __restrict__ Vp,
                                                     float* __restrict__ NV2,
                                                     float scale) {
  __shared__ float sbv[4];
  int t = threadIdx.x, lane = t & 63, wv = t >> 6;
  float var = pvar_reduce(PVAR, sbv);
  float4 mu4 = ((const float4*)MU)[lane];
  float4 bb4 = ((const float4*)BIAS)[lane];
  float mu2 = SCAL[0], lam_mu = SCAL[1], bias2 = SCAL[2], lam_bias = SCAL[3],
        mubias = SCAL[4];
  float rstd = sqrtf(WEIGHT[0] / fmaxf(var, EPSF));
  float mm[4] = {mu4.x, mu4.y, mu4.z, mu4.w};
  float bs[4] = {bb4.x, bb4.y, bb4.z, bb4.w};
  int cb = lane >> 1, e = (lane & 1) * 4;
  for (int it = 0; it < 8; ++it) {
    int pix = blockIdx.x * 32 + it * 4 + wv;
    float x[4], hn2, lamx;
    load_h(Y, Y2S, pix, lane, x, hn2, lamx);
    float r[4], nr;
    bn_core<true>(x, mm, bs, mu2, lam_mu, bias2, lam_bias, mubias, rstd, r, nr);
    float tf = atanh_fast(fminf(nr, CLIP1)) * frcp(nr);
    float tr[4];
#pragma unroll
    for (int k = 0; k < 4; ++k) tr[k] = fmaxf(tf * r[k], 0.f);
    float nt2 = wred(tr[0] * tr[0] + tr[1] * tr[1] + tr[2] * tr[2] + tr[3] * tr[3]);
    int b = pix >> 10, hh = (pix >> 5) & 31, ww = pix & 31;
    ushort4 vb;
    vb.x = f2bf(tr[0] * scale); vb.y = f2bf(tr[1] * scale);
    vb.z = f2bf(tr[2] * scale); vb.w = f2bf(tr[3] * scale);
    *(ushort4*)(Vp + ((size_t)(((b * 34 + hh + 1) * 32 + cb)) * 34 + (ww + 1)) * 8 + e) = vb;
    if (lane == 0) NV2[pix] = nt2 * scale * scale;
  }
}

// ---------------------------------------------------------------- BN2 transform + residual(from X) + hrelu + [B,C,H,W] store
__global__ __launch_bounds__(256) void k_bntrans_out(const _Float16* __restrict__ Y,
                                                     const float* __restrict__ Y2S,
                                                     const float* __restrict__ MU,
                                                     const float* __restrict__ SCAL,
                                                     const float* __restrict__ BIAS,
                                                     const float* __restrict__ WEIGHT,
                                                     const float* __restrict__ PVAR,
                                                     const float* __restrict__ X,
                                                     float* __restrict__ Out) {
  __shared__ float tile[256 * 33];
  __shared__ float tile2[256 * 33];
  __shared__ float sbv[4];
  int t = threadIdx.x, lane = t & 63, wv = t >> 6;
  int b = blockIdx.x >> 5, h = blockIdx.x & 31;
  for (int c0 = 0; c0 < 256; c0 += 8) {
    int c = c0 + (t >> 5), w = t & 31;
    tile2[c * 33 + w] = X[((b * 256 + c) * 32 + h) * 32 + w];
  }
  float var = pvar_reduce(PVAR, sbv);   // includes __syncthreads (covers tile2)
  float4 mu4 = ((const float4*)MU)[lane];
  float4 bb4 = ((const float4*)BIAS)[lane];
  float mu2 = SCAL[0], lam_mu = SCAL[1], bias2 = SCAL[2], lam_bias = SCAL[3],
        mubias = SCAL[4];
  float rstd = sqrtf(WEIGHT[0] / fmaxf(var, EPSF));
  float mm[4] = {mu4.x, mu4.y, mu4.z, mu4.w};
  float bs[4] = {bb4.x, bb4.y, bb4.z, bb4.w};
  int pix0 = blockIdx.x * 32;
  for (int it = 0; it < 8; ++it) {
    int p = it * 4 + wv;
    int pix = pix0 + p;
    float x[4], hn2, lamx;
    load_h(Y, Y2S, pix, lane, x, hn2, lamx);
    float r[4], nr;
    bn_core<true>(x, mm, bs, mu2, lam_mu, bias2, lam_bias, mubias, rstd, r, nr);
    float h2 = nr * nr;
    float rr[4];
#pragma unroll
    for (int k = 0; k < 4; ++k) rr[k] = tile2[(lane * 4 + k) * 33 + p];
    float y2r = wred(rr[0] * rr[0] + rr[1] * rr[1] + rr[2] * rr[2] + rr[3] * rr[3]);
    float xyr = wred(r[0] * rr[0] + r[1] * rr[1] + r[2] * rr[2] + r[3] * rr[3]);
    float Pm = 1.f + 2.f * xyr + y2r, Qm = 1.f - h2;
    float denmi = frcp(fmaxf(1.f + 2.f * xyr + h2 * y2r, EPSF));
#pragma unroll
    for (int k = 0; k < 4; ++k) r[k] = (Pm * r[k] + Qm * rr[k]) * denmi;
    float nr2 = wred(r[0] * r[0] + r[1] * r[1] + r[2] * r[2] + r[3] * r[3]);
    nr = sqrtf(fmaxf(nr2, EPSF));
    float tf = atanh_fast(fminf(nr, CLIP1)) * frcp(nr);
    float tr[4];
#pragma unroll
    for (int k = 0; k < 4; ++k) tr[k] = fmaxf(tf * r[k], 0.f);
    float nt2 = wred(tr[0] * tr[0] + tr[1] * tr[1] + tr[2] * tr[2] + tr[3] * tr[3]);
    float nt = sqrtf(fmaxf(nt2, EPSF));
    float une = tanh_fast(nt);
    float ef = une * frcp(nt);
    if (une > MAXNRM) ef *= MAXNRM / une;
#pragma unroll
    for (int k = 0; k < 4; ++k) tile[(lane * 4 + k) * 33 + p] = ef * tr[k];
  }
  __syncthreads();
  for (int c0 = 0; c0 < 256; c0 += 8) {
    int c = c0 + (t >> 5), w = t & 31;
    Out[((b * 256 + c) * 32 + h) * 32 + w] = tile[c * 33 + w];
  }
}

// ---------------------------------------------------------------- launch
extern "C" void kernel_launch(void* const* d_in, const int* in_sizes, int n_in,
                              void* d_out, int out_size, void* d_ws, size_t ws_size,
                              hipStream_t stream) {
  (void)in_sizes; (void)n_in; (void)out_size; (void)ws_size;
  const float* x  = (const float*)d_in[0];
  const float* z1 = (const float*)d_in[1];
  const float* z2 = (const float*)d_in[2];
  const float* w1 = (const float*)d_in[3];
  const float* b1 = (const float*)d_in[4];
  const float* w2 = (const float*)d_in[5];
  const float* b2 = (const float*)d_in[6];
  float* out = (float*)d_out;
  float* ws = (float*)d_ws;

  float* zn2     = ws;              // 512
  float* mu      = ws + 768;        // 256
  float* scal    = ws + 1024;       // 8
  float* pden    = ws + 1088;       // 128
  float* pvar    = ws + 1216;       // 128
  float* pnum    = ws + 1344;       // 256*128 = 32768
  float* y2s     = ws + 34112;      // 16384*4
  float* nv2     = ws + 99648;      // 16384
  _Float16* Y    = (_Float16*)(ws + 116032);   // 8 MB
  ushort* Vp     = (ushort*)(ws + 2213184);    // Vp2: 16*34*32*34*8 = 9.47 MB
  ushort* ZF     = Vp + 4734976;               // 2 x 589824

  double lb = (lgamma(1152.0) - lgamma(1152.5)) - (lgamma(128.0) - lgamma(128.5));
  float scale = (float)exp(lb);

  hipMemsetAsync(ws, 0, 512 * sizeof(float), stream);   // zn2
  k_zpack<<<dim3(72, 2), 256, 0, stream>>>(z1, z2, ZF, zn2);

  // ---- conv1
  k_pre1<<<512, 256, 0, stream>>>(x, Vp, nv2, scale);   // also zeroes Vp borders
  k_gemm_mfma<<<512, 256, 0, stream>>>(Vp, ZF, zn2, nv2, Y, y2s);
  k_bnsum<<<128, 256, 0, stream>>>(Y, y2s, pnum, pden);
  k_bnmid<<<1, 256, 0, stream>>>(pnum, pden, b1, mu, scal);
  k_bnvar<<<128, 256, 0, stream>>>(Y, y2s, mu, scal, pvar);
  k_bntrans_pre<<<512, 256, 0, stream>>>(Y, y2s, mu, scal, b1, w1, pvar, Vp, nv2, scale);

  // ---- conv2
  k_gemm_mfma<<<512, 256, 0, stream>>>(Vp, ZF + 589824, zn2 + 256, nv2, Y, y2s);
  k_bnsum<<<128, 256, 0, stream>>>(Y, y2s, pnum, pden);
  k_bnmid<<<1, 256, 0, stream>>>(pnum, pden, b2, mu, scal);
  k_bnvar<<<128, 256, 0, stream>>>(Y, y2s, mu, scal, pvar);
  k_bntrans_out<<<512, 256, 0, stream>>>(Y, y2s, mu, scal, b2, w2, pvar, x, out);
}

// Round 13
// 262.161 us; speedup vs baseline: 1.0650x; 1.0650x over previous
//
#include <hip/hip_runtime.h>
#include <math.h>

#define EPSF   1e-15f
#define CLIP1  0.99999988f   /* fp32(1 - 1e-7) */
#define MAXNRM 0.99999f      /* (1 - 1e-5)/sqrt(c), c = 1 */
#define LOG2E  1.44269504088896f
#define LN2    0.69314718055994f

typedef __bf16 bf16x8 __attribute__((ext_vector_type(8)));
typedef float floatx4 __attribute__((ext_vector_type(4)));
typedef _Float16 half4 __attribute__((ext_vector_type(4)));

// Vp2 element index: [b][h:34][cb:32][w:34][8]  (ushort elements)
// addr = (((b*34 + h)*32 + cb)*34 + w)*8 + e ; cb-stride = 272, h-stride = 8704

// ---------------------------------------------------------------- utilities
__device__ __forceinline__ float wred(float x) {
#pragma unroll
  for (int o = 32; o; o >>= 1) x += __shfl_xor(x, o);
  return x;
}

__device__ __forceinline__ float frcp(float x) { return __builtin_amdgcn_rcpf(x); }
__device__ __forceinline__ float flog2(float x) { return __builtin_amdgcn_logf(x); }
__device__ __forceinline__ float fexp2(float x) { return __builtin_amdgcn_exp2f(x); }

__device__ __forceinline__ float atanh_fast(float x) {   // x in [0, CLIP1]
  return 0.5f * LN2 * flog2((1.f + x) * frcp(1.f - x));
}
__device__ __forceinline__ float tanh_fast(float x) {    // x >= 0
  float q = fexp2(fminf(2.f * LOG2E * x, 126.f));
  return (q - 1.f) * frcp(q + 1.f);
}
// sinh(2*z*asinh(w)), z > 0
__device__ __forceinline__ float sinh2zasinh(float z, float w) {
  float aw = fabsf(w);
  float tt = aw + sqrtf(fmaf(aw, aw, 1.f));
  float k2 = fminf(2.f * z * flog2(tt), 126.f);
  float q = fexp2(k2);
  return copysignf(0.5f * (q - frcp(q)), w);
}

__device__ __forceinline__ unsigned short f2bf(float f) {
  unsigned int u = __float_as_uint(f);
  u += 0x7fffu + ((u >> 16) & 1u);   // RNE
  return (unsigned short)(u >> 16);
}

__device__ __forceinline__ void gl_lds16(const ushort* g, ushort* l) {
  __builtin_amdgcn_global_load_lds(
      (const __attribute__((address_space(1))) void*)g,
      (__attribute__((address_space(3))) void*)l, 16, 0, 0);
}

// ---------------------------------------------------------------- Z -> fragment-ordered bf16 (+ column norms^2)
__global__ __launch_bounds__(256) void k_zpack(const float* __restrict__ Z1,
                                               const float* __restrict__ Z2,
                                               ushort* __restrict__ ZF,
                                               float* __restrict__ ZN2) {
  __shared__ float zs[32 * 256];
  int kt = blockIdx.x, mat = blockIdx.y;
  const float* Z = mat ? Z2 : Z1;
  ushort* out = ZF + (size_t)mat * 589824;
  int t = threadIdx.x;
  const float4* src = (const float4*)(Z + kt * 32 * 256);
  float4* dst4 = (float4*)zs;
#pragma unroll
  for (int i = 0; i < 8; ++i) dst4[t + i * 256] = src[t + i * 256];
  __syncthreads();
  {
    float acc = 0.f;
#pragma unroll 8
    for (int k = 0; k < 32; ++k) {
      float z = zs[k * 256 + t];
      acc = fmaf(z, z, acc);
    }
    atomicAdd(&ZN2[mat * 256 + t], acc);
  }
  int l = t & 63, sub = t >> 6;
  for (int i = 0; i < 4; ++i) {
    int combo = sub * 4 + i;                 // ctg 0..15
    int col = combo * 16 + (l & 15);
    int krow = (l >> 4) * 8;
    unsigned int pk[4];
#pragma unroll
    for (int j = 0; j < 4; ++j) {
      unsigned int lo = f2bf(zs[(krow + 2 * j) * 256 + col]);
      unsigned int hi = f2bf(zs[(krow + 2 * j + 1) * 256 + col]);
      pk[j] = lo | (hi << 16);
    }
    uint4* o = (uint4*)(out + ((size_t)(kt * 16 + combo)) * 512 + l * 8);
    *o = make_uint4(pk[0], pk[1], pk[2], pk[3]);
  }
}

// ---------------------------------------------------------------- x[B,C,H,W] -> Vp2 bf16 (channel-blocked), nv2
__global__ __launch_bounds__(256) void k_pre1(const float* __restrict__ X,
                                              ushort* __restrict__ Vp,
                                              float* __restrict__ NV2,
                                              float scale) {
  __shared__ float tile[256 * 33];
  __shared__ float facs[32];
  const int b = blockIdx.x >> 5, h = blockIdx.x & 31;
  const int t = threadIdx.x;
  for (int c0 = 0; c0 < 256; c0 += 8) {
    int c = c0 + (t >> 5), w = t & 31;
    tile[c * 33 + w] = X[((b * 256 + c) * 32 + h) * 32 + w];
  }
  __syncthreads();
  {
    int w = t >> 3, s = t & 7;
    float n2 = 0.f;
#pragma unroll 8
    for (int i = 0; i < 32; ++i) {
      float xv = tile[(s + 8 * i) * 33 + w];
      n2 = fmaf(xv, xv, n2);
    }
    n2 += __shfl_xor(n2, 1); n2 += __shfl_xor(n2, 2); n2 += __shfl_xor(n2, 4);
    float n = sqrtf(fmaxf(n2, EPSF));
    float fac = atanh_fast(fminf(n, CLIP1)) * frcp(n) * scale;
    if (s == 0) {
      facs[w] = fac;
      NV2[blockIdx.x * 32 + w] = fac * fac * n2;
    }
  }
  __syncthreads();
  const int g = t & 63;
  const int cb = g >> 1, e = (g & 1) * 4;
  const int Hrow = (b * 34 + h + 1) * 32;
#pragma unroll
  for (int it = 0; it < 8; ++it) {
    int p = (t >> 6) + it * 4;
    float f = facs[p];
    ushort4 vb;
    vb.x = f2bf(tile[(g * 4 + 0) * 33 + p] * f);
    vb.y = f2bf(tile[(g * 4 + 1) * 33 + p] * f);
    vb.z = f2bf(tile[(g * 4 + 2) * 33 + p] * f);
    vb.w = f2bf(tile[(g * 4 + 3) * 33 + p] * f);
    *(ushort4*)(Vp + ((size_t)(Hrow + cb) * 34 + (p + 1)) * 8 + e) = vb;
  }
}

// ---------------------------------------------------------------- MFMA implicit-GEMM conv + fused Poincare-FC front
// tile 128 rows x 64 cols, 4 waves x 32 rows (B-frag reuse x2), grid 512 (2 blocks/CU).
// A: regs from coalesced Vp2 (explicit dbuf, compile-time indices). B: 8KB LDS dbuf.
__global__ __launch_bounds__(256) void k_gemm_mfma(const ushort* __restrict__ Vp,
                                                   const ushort* __restrict__ ZF,
                                                   const float* __restrict__ ZN2,
                                                   const float* __restrict__ NV2,
                                                   _Float16* __restrict__ Y,
                                                   float* __restrict__ Y2S) {
  __shared__ ushort ldsB[8192];   // 2 bufs x 4KB
  __shared__ float lfs[128];
  const int t = threadIdx.x;
  const int wv = t >> 6, l = t & 63;
  const int l15 = l & 15, l16 = l >> 4;
  const int g = blockIdx.x;
  const int xcd = g & 7, gi = g >> 3;
  const int rowb = (gi >> 2) * 8 + xcd;       // 0..127
  const int colb = gi & 3;                    // 0..3
  const int col0 = colb * 64, row0 = rowb * 128;
  const int cb4 = colb * 4;

  // preamble: LF for this block's 128 rows (fused boxsum)
  if (t < 128) {
    int r = row0 + t;
    int hw = r & 1023, hh = hw >> 5, ww = hw & 31, base = r & ~1023;
    float s = 0.f;
#pragma unroll
    for (int di = -1; di <= 1; ++di)
#pragma unroll
      for (int dj = -1; dj <= 1; ++dj) {
        int sh = hh + di, sw = ww + dj;
        if ((unsigned)sh < 32u && (unsigned)sw < 32u) s += NV2[base + sh * 32 + sw];
      }
    float np = sqrtf(fmaxf(s, EPSF));
    float un = tanh_fast(np);
    float f = un * frcp(np);
    if (un > MAXNRM) f *= MAXNRM / un;
    float u2 = f * f * s;
    lfs[t] = 2.f * frcp(fmaxf(1.f - u2, EPSF)) * f;
  }

  // per-lane A bases for this wave's 32 rows (two 16-row tiles); rbase is 32-aligned
  const int rbase = row0 + wv * 32;
  const int pb = rbase >> 10, ph = (rbase >> 5) & 31;
  const int Hrow = (pb * 34 + ph + 1) * 32;
  int abase[2];
#pragma unroll
  for (int rt = 0; rt < 2; ++rt)
    abase[rt] = Hrow * 272 + (1 + rt * 16 + l15) * 8 + l16 * 272;

  floatx4 acc[2][4];
#pragma unroll
  for (int rt = 0; rt < 2; ++rt)
#pragma unroll
    for (int j = 0; j < 4; ++j) acc[rt][j] = (floatx4){0.f, 0.f, 0.f, 0.f};

  auto loadA = [&](bf16x8 (&ar)[2][2], int kt) {   // [s][rt]
    int tap = kt >> 2;
    int di = tap / 3 - 1, dj = tap % 3 - 1;
    int koff = (di * 32 + (kt & 3) * 8) * 272 + dj * 8;   // wave-uniform
#pragma unroll
    for (int s = 0; s < 2; ++s)
#pragma unroll
      for (int rt = 0; rt < 2; ++rt)
        ar[s][rt] = *(const bf16x8*)(Vp + abase[rt] + koff + s * 1088);
  };
  auto stageB = [&](int buf, int kt) {
    ushort* Bd = ldsB + buf * 4096;
#pragma unroll
    for (int ii = 0; ii < 2; ++ii) {
      int bj = wv + ii * 4;                 // 0..7 = s*4 + ct
      int s = bj >> 2, ct = bj & 3;
      gl_lds16(ZF + ((size_t)((kt * 2 + s) * 16 + cb4 + ct)) * 512 + l * 8,
               Bd + bj * 512);
    }
  };
  auto compute = [&](const bf16x8 (&ar)[2][2], const ushort* Bb) {
    bf16x8 b[2][4];
#pragma unroll
    for (int s = 0; s < 2; ++s)
#pragma unroll
      for (int j = 0; j < 4; ++j)
        b[s][j] = *(const bf16x8*)(Bb + (s * 4 + j) * 512 + l * 8);
#pragma unroll
    for (int s = 0; s < 2; ++s)
#pragma unroll
      for (int rt = 0; rt < 2; ++rt)
#pragma unroll
        for (int j = 0; j < 4; ++j)
          acc[rt][j] = __builtin_amdgcn_mfma_f32_16x16x32_bf16(ar[s][rt], b[s][j],
                                                               acc[rt][j], 0, 0, 0);
  };

  bf16x8 aA[2][2], aB[2][2];
  stageB(0, 0);
  loadA(aA, 0);
  for (int kt = 0; kt < 36; kt += 2) {
    __syncthreads();                         // B(kt) resident in buf 0
    stageB(1, kt + 1);
    loadA(aB, kt + 1);
    compute(aA, ldsB);
    __syncthreads();                         // B(kt+1) resident in buf 1
    if (kt + 2 < 36) {
      stageB(0, kt + 2);
      loadA(aA, kt + 2);
    }
    compute(aB, ldsB + 4096);
  }

  // fused epilogue: y fp16 + per-colblock y^2 slice (no atomics)
  float zns[4], izns[4];
#pragma unroll
  for (int j = 0; j < 4; ++j) {
    int c = col0 + j * 16 + l15;
    float zn = sqrtf(fmaxf(ZN2[c], EPSF));
    zns[j] = zn;
    izns[j] = frcp(zn);
  }
#pragma unroll
  for (int rt = 0; rt < 2; ++rt) {
#pragma unroll
    for (int reg = 0; reg < 4; ++reg) {
      int rl = wv * 32 + rt * 16 + l16 * 4 + reg;
      int r = row0 + rl;
      float lf = lfs[rl];
      float part = 0.f;
#pragma unroll
      for (int j = 0; j < 4; ++j) {
        float yv = sinh2zasinh(zns[j], lf * acc[rt][j][reg] * izns[j]);
        Y[(size_t)r * 256 + col0 + j * 16 + l15] = (_Float16)yv;
        part = fmaf(yv, yv, part);
      }
      part += __shfl_xor(part, 1);
      part += __shfl_xor(part, 2);
      part += __shfl_xor(part, 4);
      part += __shfl_xor(part, 8);
      if (l15 == 0) Y2S[r * 4 + colb] = part;
    }
  }
}

// ---------------------------------------------------------------- recompute h from (Y, Y2 slices)
__device__ __forceinline__ void load_h(const _Float16* Y, const float* Y2S,
                                       int pix, int lane, float h[4],
                                       float& hn2, float& lam) {
  half4 y4 = ((const half4*)Y)[pix * 64 + lane];
  float4 q = ((const float4*)Y2S)[pix];
  float y2 = (q.x + q.y) + (q.z + q.w);
  float inv = frcp(1.f + sqrtf(1.f + y2));
  h[0] = (float)y4.x * inv; h[1] = (float)y4.y * inv;
  h[2] = (float)y4.z * inv; h[3] = (float)y4.w * inv;
  hn2 = y2 * inv * inv;
  lam = 2.f * frcp(fmaxf(1.f - hn2, EPSF));
}

// ---------------------------------------------------------------- BN reduction 1 (partials)
__global__ __launch_bounds__(256) void k_bnsum(const _Float16* __restrict__ Y,
                                               const float* __restrict__ Y2S,
                                               float* __restrict__ PNUM,
                                               float* __restrict__ PDEN) {
  __shared__ float snum[256];
  __shared__ float sden;
  int t = threadIdx.x, lane = t & 63, wv = t >> 6;
  snum[t] = 0.f;
  if (t == 0) sden = 0.f;
  __syncthreads();
  float acc[4] = {0.f, 0.f, 0.f, 0.f};
  float accd = 0.f;
  for (int it = 0; it < 8; ++it) {
    int pix = blockIdx.x * 32 + it * 4 + wv;
    float h[4], hn2, lam;
    load_h(Y, Y2S, pix, lane, h, hn2, lam);
#pragma unroll
    for (int k = 0; k < 4; ++k) acc[k] = fmaf(lam, h[k], acc[k]);
    if (lane == 0) accd += lam - 1.f;
  }
  atomicAdd(&snum[lane * 4 + 0], acc[0]);
  atomicAdd(&snum[lane * 4 + 1], acc[1]);
  atomicAdd(&snum[lane * 4 + 2], acc[2]);
  atomicAdd(&snum[lane * 4 + 3], acc[3]);
  if (lane == 0) atomicAdd(&sden, accd);
  __syncthreads();
  PNUM[t * 512 + blockIdx.x] = snum[t];
  if (t == 0) PDEN[blockIdx.x] = sden;
}

// ---------------------------------------------------------------- BN midpoint + scalars (reduces partials)
__global__ __launch_bounds__(256) void k_bnmid(const float* __restrict__ PNUM,
                                               const float* __restrict__ PDEN,
                                               const float* __restrict__ BIAS,
                                               float* __restrict__ MU,
                                               float* __restrict__ SCAL) {
  __shared__ float sb[4];
  int t = threadIdx.x, lane = t & 63, wv = t >> 6;
  auto bred = [&](float v) {
    v = wred(v);
    __syncthreads();
    if (lane == 0) sb[wv] = v;
    __syncthreads();
    return sb[0] + sb[1] + sb[2] + sb[3];
  };
  float num = 0.f;
  const float4* pn = (const float4*)(PNUM + t * 512);
#pragma unroll 8
  for (int i = 0; i < 128; ++i) {
    float4 v = pn[i];
    num += (v.x + v.y) + (v.z + v.w);
  }
  float den = bred(PDEN[t] + PDEN[t + 256]);
  float m = num / fmaxf(den, EPSF);
  float n2m = bred(m * m);
  float n = sqrtf(fmaxf(n2m, EPSF));
  float midf = tanh_fast(0.5f * atanh_fast(fminf(n, CLIP1))) * frcp(n);
  float mu = m * midf;
  MU[t] = mu;
  float bv = BIAS[t];
  float bias2 = bred(bv * bv);
  float mubias = bred(bv * mu);
  if (t == 0) {
    float mu2 = midf * midf * n2m;
    SCAL[0] = mu2;
    SCAL[1] = 2.f / fmaxf(1.f - mu2, EPSF);
    SCAL[2] = bias2;
    SCAL[3] = 2.f / fmaxf(1.f - bias2, EPSF);
    SCAL[4] = mubias;
  }
}

// ---------------------------------------------------------------- BN reduction 2 (var partials)
__global__ __launch_bounds__(256) void k_bnvar(const _Float16* __restrict__ Y,
                                               const float* __restrict__ Y2S,
                                               const float* __restrict__ MU,
                                               const float* __restrict__ SCAL,
                                               float* __restrict__ PVAR) {
  __shared__ float sp[4];
  int t = threadIdx.x, lane = t & 63, wv = t >> 6;
  float4 muv = ((const float4*)MU)[lane];
  float mu2 = SCAL[0];
  float accd = 0.f;
  for (int it = 0; it < 8; ++it) {
    int pix = blockIdx.x * 32 + it * 4 + wv;
    float h[4], x2, lam;
    load_h(Y, Y2S, pix, lane, h, x2, lam);
    float xmu = wred(h[0] * muv.x + h[1] * muv.y + h[2] * muv.z + h[3] * muv.w);
    float A = 1.f - 2.f * xmu + mu2;
    float B = 1.f - x2;
    float num2 = A * A * x2 + B * B * mu2 - 2.f * A * B * xmu;
    float den = fmaxf(1.f - 2.f * xmu + x2 * mu2, EPSF);
    float nn = sqrtf(fmaxf(num2, EPSF)) * frcp(den);
    float dist = 2.f * atanh_fast(fminf(nn, CLIP1));
    accd += dist * dist;
  }
  if (lane == 0) sp[wv] = accd;
  __syncthreads();
  if (t == 0) PVAR[blockIdx.x] = sp[0] + sp[1] + sp[2] + sp[3];
}

// ---------------------------------------------------------------- BN transform core
template <bool CLIPR>
__device__ __forceinline__ void bn_core(const float x[4], const float mm[4],
                                        const float bs[4], float mu2, float lam_mu,
                                        float bias2, float lam_bias, float mubias,
                                        float rstd, float r[4], float& nr) {
  float x2 = wred(x[0] * x[0] + x[1] * x[1] + x[2] * x[2] + x[3] * x[3]);
  float xmu = wred(x[0] * mm[0] + x[1] * mm[1] + x[2] * mm[2] + x[3] * mm[3]);
  float P = 1.f - 2.f * xmu + x2, Q = 1.f - mu2;
  float den1i = frcp(fmaxf(1.f - 2.f * xmu + mu2 * x2, EPSF));
  float d[4];
#pragma unroll
  for (int k = 0; k < 4; ++k) d[k] = (Q * x[k] - P * mm[k]) * den1i;
  float nd2 = wred(d[0] * d[0] + d[1] * d[1] + d[2] * d[2] + d[3] * d[3]);
  float nd = sqrtf(fmaxf(nd2, EPSF));
  float vfac = (2.f / lam_mu) * atanh_fast(fminf(nd, CLIP1)) * frcp(nd);
  float v[4];
#pragma unroll
  for (int k = 0; k < 4; ++k) v[k] = vfac * d[k];
  float uw = wred(bs[0] * v[0] + bs[1] * v[1] + bs[2] * v[2] + bs[3] * v[3]);
  float mv = wred(mm[0] * v[0] + mm[1] * v[1] + mm[2] * v[2] + mm[3] * v[3]);
  float vw = -mv, uv = -mubias;
  float ga = -(uw * mu2) - vw + 2.f * uv * vw;
  float gb = -(vw * bias2) + uw;
  float ddi = frcp(fmaxf(1.f + 2.f * uv + bias2 * mu2, EPSF));
  float sgy = (lam_mu / lam_bias) * rstd;
  float u[4];
#pragma unroll
  for (int k = 0; k < 4; ++k)
    u[k] = (v[k] + 2.f * (ga * bs[k] - gb * mm[k]) * ddi) * sgy;
  float nu2 = wred(u[0] * u[0] + u[1] * u[1] + u[2] * u[2] + u[3] * u[3]);
  float bu = wred(bs[0] * u[0] + bs[1] * u[1] + bs[2] * u[2] + bs[3] * u[3]);
  float nu = sqrtf(fmaxf(nu2, EPSF));
  float sfac = tanh_fast(lam_bias * nu * 0.5f) * frcp(nu);
  float y2 = sfac * sfac * nu2, xy = sfac * bu;
  float P2 = 1.f + 2.f * xy + y2, Q2 = 1.f - bias2;
  float den2i = frcp(fmaxf(1.f + 2.f * xy + bias2 * y2, EPSF));
#pragma unroll
  for (int k = 0; k < 4; ++k) r[k] = (P2 * bs[k] + Q2 * sfac * u[k]) * den2i;
  float nr2 = wred(r[0] * r[0] + r[1] * r[1] + r[2] * r[2] + r[3] * r[3]);
  nr = sqrtf(fmaxf(nr2, EPSF));
  if (CLIPR && nr > MAXNRM) {
    float sc = MAXNRM / nr;
#pragma unroll
    for (int k = 0; k < 4; ++k) r[k] *= sc;
    nr = MAXNRM;
  }
}

// reduce 512 PVAR partials to var (all threads get result)
__device__ __forceinline__ float pvar_reduce(const float* PVAR, float* sbv) {
  int t = threadIdx.x, lane = t & 63, wv = t >> 6;
  float pv = wred(PVAR[t] + PVAR[t + 256]);
  __syncthreads();
  if (lane == 0) sbv[wv] = pv;
  __syncthreads();
  return (sbv[0] + sbv[1] + sbv[2] + sbv[3]) * (1.f / 16384.f);
}

// ---------------------------------------------------------------- BN1 transform + hrelu + logmap0*scale -> Vp2,NV2
__global__ __launch_bounds__(256) void k_bntrans_pre(const _Float16* __restrict__ Y,
                                                     const float* __restrict__ Y2S,
                                                     const float* __restrict__ MU,
                                                     const float* __restrict__ SCAL,
                                                     const float* __restrict__ BIAS,
                                                     const float* __restrict__ WEIGHT,
                                                     const float* __restrict__ PVAR,
                                                     ushort* __restrict__ Vp,
                                                     float* __restrict__ NV2,
                                                     float scale) {
  __shared__ float sbv[4];
  int pix = blockIdx.x * 4 + (threadIdx.x >> 6);
  int lane = threadIdx.x & 63;
  float var = pvar_reduce(PVAR, sbv);
  float4 mu4 = ((const float4*)MU)[lane];
  float4 bb4 = ((const float4*)BIAS)[lane];
  float mu2 = SCAL[0], lam_mu = SCAL[1], bias2 = SCAL[2], lam_bias = SCAL[3],
        mubias = SCAL[4];
  float rstd = sqrtf(WEIGHT[0] / fmaxf(var, EPSF));
  float x[4], hn2, lamx;
  load_h(Y, Y2S, pix, lane, x, hn2, lamx);
  float mm[4] = {mu4.x, mu4.y, mu4.z, mu4.w};
  float bs[4] = {bb4.x, bb4.y, bb4.z, bb4.w};
  float r[4], nr;
  bn_core<true>(x, mm, bs, mu2, lam_mu, bias2, lam_bias, mubias, rstd, r, nr);
  float tf = atanh_fast(fminf(nr, CLIP1)) * frcp(nr);
  float tr[4];
#pragma unroll
  for (int k = 0; k < 4; ++k) tr[k] = fmaxf(tf * r[k], 0.f);
  float nt2 = wred(tr[0] * tr[0] + tr[1] * tr[1] + tr[2] * tr[2] + tr[3] * tr[3]);
  int b = pix >> 10, hh = (pix >> 5) & 31, ww = pix & 31;
  ushort4 vb;
  vb.x = f2bf(tr[0] * scale); vb.y = f2bf(tr[1] * scale);
  vb.z = f2bf(tr[2] * scale); vb.w = f2bf(tr[3] * scale);
  int cb = lane >> 1, e = (lane & 1) * 4;
  *(ushort4*)(Vp + ((size_t)(((b * 34 + hh + 1) * 32 + cb)) * 34 + (ww + 1)) * 8 + e) = vb;
  if (lane == 0) NV2[pix] = nt2 * scale * scale;
}

// ---------------------------------------------------------------- BN2 transform + residual(from X) + hrelu + [B,C,H,W] store
__global__ __launch_bounds__(256) void k_bntrans_out(const _Float16* __restrict__ Y,
                                                     const float* __restrict__ Y2S,
                                                     const float* __restrict__ MU,
                                                     const float* __restrict__ SCAL,
                                                     const float* __restrict__ BIAS,
                                                     const float* __restrict__ WEIGHT,
                                                     const float* __restrict__ PVAR,
                                                     const float* __restrict__ X,
                                                     float* __restrict__ Out) {
  __shared__ float tile[256 * 33];
  __shared__ float tile2[256 * 33];
  __shared__ float sbv[4];
  int t = threadIdx.x, lane = t & 63, wv = t >> 6;
  int b = blockIdx.x >> 5, h = blockIdx.x & 31;
  for (int c0 = 0; c0 < 256; c0 += 8) {
    int c = c0 + (t >> 5), w = t & 31;
    tile2[c * 33 + w] = X[((b * 256 + c) * 32 + h) * 32 + w];
  }
  float var = pvar_reduce(PVAR, sbv);   // includes __syncthreads (covers tile2)
  float4 mu4 = ((const float4*)MU)[lane];
  float4 bb4 = ((const float4*)BIAS)[lane];
  float mu2 = SCAL[0], lam_mu = SCAL[1], bias2 = SCAL[2], lam_bias = SCAL[3],
        mubias = SCAL[4];
  float rstd = sqrtf(WEIGHT[0] / fmaxf(var, EPSF));
  float mm[4] = {mu4.x, mu4.y, mu4.z, mu4.w};
  float bs[4] = {bb4.x, bb4.y, bb4.z, bb4.w};
  int pix0 = blockIdx.x * 32;
  for (int it = 0; it < 8; ++it) {
    int p = it * 4 + wv;
    int pix = pix0 + p;
    float x[4], hn2, lamx;
    load_h(Y, Y2S, pix, lane, x, hn2, lamx);
    float r[4], nr;
    bn_core<true>(x, mm, bs, mu2, lam_mu, bias2, lam_bias, mubias, rstd, r, nr);
    float h2 = nr * nr;
    float rr[4];
#pragma unroll
    for (int k = 0; k < 4; ++k) rr[k] = tile2[(lane * 4 + k) * 33 + p];
    float y2r = wred(rr[0] * rr[0] + rr[1] * rr[1] + rr[2] * rr[2] + rr[3] * rr[3]);
    float xyr = wred(r[0] * rr[0] + r[1] * rr[1] + r[2] * rr[2] + r[3] * rr[3]);
    float Pm = 1.f + 2.f * xyr + y2r, Qm = 1.f - h2;
    float denmi = frcp(fmaxf(1.f + 2.f * xyr + h2 * y2r, EPSF));
#pragma unroll
    for (int k = 0; k < 4; ++k) r[k] = (Pm * r[k] + Qm * rr[k]) * denmi;
    float nr2 = wred(r[0] * r[0] + r[1] * r[1] + r[2] * r[2] + r[3] * r[3]);
    nr = sqrtf(fmaxf(nr2, EPSF));
    float tf = atanh_fast(fminf(nr, CLIP1)) * frcp(nr);
    float tr[4];
#pragma unroll
    for (int k = 0; k < 4; ++k) tr[k] = fmaxf(tf * r[k], 0.f);
    float nt2 = wred(tr[0] * tr[0] + tr[1] * tr[1] + tr[2] * tr[2] + tr[3] * tr[3]);
    float nt = sqrtf(fmaxf(nt2, EPSF));
    float une = tanh_fast(nt);
    float ef = une * frcp(nt);
    if (une > MAXNRM) ef *= MAXNRM / une;
#pragma unroll
    for (int k = 0; k < 4; ++k) tile[(lane * 4 + k) * 33 + p] = ef * tr[k];
  }
  __syncthreads();
  for (int c0 = 0; c0 < 256; c0 += 8) {
    int c = c0 + (t >> 5), w = t & 31;
    Out[((b * 256 + c) * 32 + h) * 32 + w] = tile[c * 33 + w];
  }
}

// ---------------------------------------------------------------- launch
extern "C" void kernel_launch(void* const* d_in, const int* in_sizes, int n_in,
                              void* d_out, int out_size, void* d_ws, size_t ws_size,
                              hipStream_t stream) {
  (void)in_sizes; (void)n_in; (void)out_size; (void)ws_size;
  const float* x  = (const float*)d_in[0];
  const float* z1 = (const float*)d_in[1];
  const float* z2 = (const float*)d_in[2];
  const float* w1 = (const float*)d_in[3];
  const float* b1 = (const float*)d_in[4];
  const float* w2 = (const float*)d_in[5];
  const float* b2 = (const float*)d_in[6];
  float* out = (float*)d_out;
  float* ws = (float*)d_ws;

  float* zn2     = ws;              // 512
  float* mu      = ws + 768;        // 256
  float* scal    = ws + 1024;       // 8
  float* pden    = ws + 1088;       // 512
  float* pvar    = ws + 1600;       // 512
  float* pnum    = ws + 2112;       // 256*512
  float* y2s     = ws + 133184;     // 16384*4
  float* nv2     = ws + 198720;     // 16384
  _Float16* Y    = (_Float16*)(ws + 215104);   // 8 MB
  ushort* Vp     = (ushort*)(ws + 2312256);    // Vp2: 16*34*32*34*8 = 9.47 MB
  ushort* ZF     = Vp + 4734976;               // 2 x 589824

  double lb = (lgamma(1152.0) - lgamma(1152.5)) - (lgamma(128.0) - lgamma(128.5));
  float scale = (float)exp(lb);

  hipMemsetAsync(ws, 0, 512 * sizeof(float), stream);   // zn2
  hipMemsetAsync(Vp, 0, (size_t)4734976 * 2, stream);   // zero padding borders
  k_zpack<<<dim3(72, 2), 256, 0, stream>>>(z1, z2, ZF, zn2);

  // ---- conv1
  k_pre1<<<512, 256, 0, stream>>>(x, Vp, nv2, scale);
  k_gemm_mfma<<<512, 256, 0, stream>>>(Vp, ZF, zn2, nv2, Y, y2s);
  k_bnsum<<<512, 256, 0, stream>>>(Y, y2s, pnum, pden);
  k_bnmid<<<1, 256, 0, stream>>>(pnum, pden, b1, mu, scal);
  k_bnvar<<<512, 256, 0, stream>>>(Y, y2s, mu, scal, pvar);
  k_bntrans_pre<<<4096, 256, 0, stream>>>(Y, y2s, mu, scal, b1, w1, pvar, Vp, nv2, scale);

  // ---- conv2
  k_gemm_mfma<<<512, 256, 0, stream>>>(Vp, ZF + 589824, zn2 + 256, nv2, Y, y2s);
  k_bnsum<<<512, 256, 0, stream>>>(Y, y2s, pnum, pden);
  k_bnmid<<<1, 256, 0, stream>>>(pnum, pden, b2, mu, scal);
  k_bnvar<<<512, 256, 0, stream>>>(Y, y2s, mu, scal, pvar);
  k_bntrans_out<<<512, 256, 0, stream>>>(Y, y2s, mu, scal, b2, w2, pvar, x, out);
}